// Round 1
// baseline (654.364 us; speedup 1.0000x reference)
//
#include <hip/hip_runtime.h>

typedef unsigned short u16;
typedef unsigned int u32;
typedef short short8 __attribute__((ext_vector_type(8)));
typedef float f32x4 __attribute__((ext_vector_type(4)));

#define T_LEN 512
#define BATCH 128
#define DIM 128
#define HID 128
#define G4H 512
#define NCLS 19
#define GATES_HALF 33554432u  // 65536*512 elements per direction

static __device__ __forceinline__ u16 f2bf(float f) {
  u32 u = __float_as_uint(f);
  u32 r = (u + 0x7FFFu + ((u >> 16) & 1u)) >> 16;
  return (u16)r;
}
static __device__ __forceinline__ float bf2f(u16 h) {
  return __uint_as_float(((u32)h) << 16);
}

// ---------------- embedding gather + cast to bf16, layout xs[t*B+b][d] -------------
__global__ __launch_bounds__(256) void k_embed(const int* __restrict__ ids,
                                               const float* __restrict__ table,
                                               u16* __restrict__ xs) {
  int i = blockIdx.x * 256 + threadIdx.x;
  int e = i * 4;               // element index, total T*B*D = 8388608
  int m = e >> 7;              // row = t*B + b
  int col = e & 127;
  int t = m >> 7, b = m & 127;
  int id = ids[b * T_LEN + t];
  float4 v = *(const float4*)(table + (size_t)id * DIM + col);
  ushort4 o;
  o.x = f2bf(v.x); o.y = f2bf(v.y); o.z = f2bf(v.z); o.w = f2bf(v.w);
  *(ushort4*)(xs + (size_t)m * DIM + col) = o;
}

// ---------------- weight prep: Wx transposed bf16 [1024][128], Wh_t fp32 [2][512][128], bias ----
__global__ __launch_bounds__(256) void k_prep(const float* __restrict__ fw_k,
                                              const float* __restrict__ bw_k,
                                              const float* __restrict__ fw_b,
                                              const float* __restrict__ bw_b,
                                              u16* __restrict__ wx_t,
                                              float* __restrict__ wh_t,
                                              float* __restrict__ bias_cat) {
  int wg = blockIdx.x;
  int tid = threadIdx.x;
  if (wg < 512) {                 // Wx_t[n][k] = K_dir[k][j], n = dir*512 + j
    int i = wg * 256 + tid;       // 0..131071
    int n = i >> 7, k = i & 127;
    int dir = n >> 9, j = n & 511;
    const float* K = dir ? bw_k : fw_k;
    wx_t[i] = f2bf(K[k * G4H + j]);
  } else if (wg < 1024) {         // Wh_t[dir][j][k] = K_dir[128+k][j]
    int i = (wg - 512) * 256 + tid;
    int dir = i >> 16;
    int j = (i >> 7) & 511, k = i & 127;
    const float* K = dir ? bw_k : fw_k;
    wh_t[i] = K[(128 + k) * G4H + j];
  } else {
    for (int u = 0; u < 4; u++) {
      int n = u * 256 + tid;
      int dir = n >> 9, j = n & 511;
      bias_cat[n] = dir ? bw_b[j] : fw_b[j];
    }
  }
}

// ---------------- input projection GEMM: [65536,128] @ [128,1024] bf16 MFMA -> bf16 gates ------
__global__ __launch_bounds__(256, 2) void k_gemm(const u16* __restrict__ xs,
                                                 const u16* __restrict__ wx_t,
                                                 const float* __restrict__ bias_cat,
                                                 u16* __restrict__ gates) {
  __shared__ u16 As[128 * 136];
  __shared__ u16 Bs[128 * 136];
  int tid = threadIdx.x;
  int m0 = blockIdx.x * 128;
  int n0 = blockIdx.y * 128;
  const u16* Asrc = xs + (size_t)m0 * 128;     // contiguous 32KB tile
  const u16* Bsrc = wx_t + (size_t)n0 * 128;   // contiguous 32KB tile (pre-transposed)
#pragma unroll
  for (int i = 0; i < 8; i++) {
    int c = i * 256 + tid;            // 0..2047 chunks of 16B
    int row = c >> 4, off = (c & 15) * 8;
    short8 va = *(const short8*)(Asrc + row * 128 + off);
    *(short8*)(As + row * 136 + off) = va;
    short8 vb = *(const short8*)(Bsrc + row * 128 + off);
    *(short8*)(Bs + row * 136 + off) = vb;
  }
  __syncthreads();
  int l = tid & 63, w = tid >> 6;
  int wm = w & 1, wn = w >> 1;
  int lr = l & 15, lk = (l >> 4) * 8;
  f32x4 acc[4][4];
#pragma unroll
  for (int a = 0; a < 4; a++)
#pragma unroll
    for (int b2 = 0; b2 < 4; b2++) acc[a][b2] = (f32x4){0.f, 0.f, 0.f, 0.f};
#pragma unroll
  for (int ks = 0; ks < 4; ks++) {
    int k = ks * 32 + lk;
    short8 af[4], bf[4];
#pragma unroll
    for (int fm = 0; fm < 4; fm++)
      af[fm] = *(const short8*)(As + (wm * 64 + fm * 16 + lr) * 136 + k);
#pragma unroll
    for (int fn = 0; fn < 4; fn++)
      bf[fn] = *(const short8*)(Bs + (wn * 64 + fn * 16 + lr) * 136 + k);
#pragma unroll
    for (int fm = 0; fm < 4; fm++)
#pragma unroll
      for (int fn = 0; fn < 4; fn++)
        acc[fm][fn] = __builtin_amdgcn_mfma_f32_16x16x32_bf16(af[fm], bf[fn], acc[fm][fn], 0, 0, 0);
  }
#pragma unroll
  for (int fm = 0; fm < 4; fm++) {
#pragma unroll
    for (int fn = 0; fn < 4; fn++) {
      int gcol = n0 + wn * 64 + fn * 16 + lr;
      int dir = gcol >> 9, j = gcol & 511;
      float bsv = bias_cat[gcol];
#pragma unroll
      for (int i2 = 0; i2 < 4; i2++) {
        int grow = m0 + wm * 64 + fm * 16 + (l >> 4) * 4 + i2;
        float v = acc[fm][fn][i2] + bsv;
        gates[(size_t)dir * GATES_HALF + (size_t)grow * 512 + j] = f2bf(v);
      }
    }
  }
}

// ---------------- persistent LSTM: 256 WGs (dir x batch), 512 threads = gate columns ----------
__global__ __launch_bounds__(512) void k_lstm(const float* __restrict__ wh_t,
                                              const u16* __restrict__ gates,
                                              float* __restrict__ hs_fw,
                                              float* __restrict__ hs_bw) {
  __shared__ float h_lds[128];
  __shared__ float z_lds[512];
  int tid = threadIdx.x;
  int wg = blockIdx.x;
  int dir = wg >> 7;
  int b = wg & 127;
  float* hs = dir ? hs_bw : hs_fw;
  const u16* g_base = gates + (size_t)dir * GATES_HALF;
  // recurrent weights for my column, fp32 in VGPRs
  float wv[128];
  const float4* wsrc = (const float4*)(wh_t + ((size_t)dir * 512 + tid) * 128);
#pragma unroll
  for (int i = 0; i < 32; i++) {
    float4 v = wsrc[i];
    wv[4 * i + 0] = v.x; wv[4 * i + 1] = v.y;
    wv[4 * i + 2] = v.z; wv[4 * i + 3] = v.w;
  }
  if (tid < 128) h_lds[tid] = 0.f;
  float c = 0.f;
  __syncthreads();
  int t_act = dir ? (T_LEN - 1) : 0;
  int step = dir ? -1 : 1;
  u16 gcur = g_base[(size_t)(t_act * 128 + b) * 512 + tid];
  for (int t = 0; t < T_LEN; t++) {
    int t_next = t_act + step;
    u16 gnxt = (t < T_LEN - 1) ? g_base[(size_t)(t_next * 128 + b) * 512 + tid] : (u16)0;
    // GEMV: z_j = sum_k h[k] * Wh[k][j]
    const float4* h4 = (const float4*)h_lds;
    float acc0 = 0.f, acc1 = 0.f;
#pragma unroll
    for (int g = 0; g < 4; g++) {
      float4 hv[8];
#pragma unroll
      for (int i = 0; i < 8; i++) hv[i] = h4[g * 8 + i];
#pragma unroll
      for (int i = 0; i < 8; i++) {
        int k = g * 32 + i * 4;
        acc0 = fmaf(wv[k + 0], hv[i].x, acc0);
        acc1 = fmaf(wv[k + 1], hv[i].y, acc1);
        acc0 = fmaf(wv[k + 2], hv[i].z, acc0);
        acc1 = fmaf(wv[k + 3], hv[i].w, acc1);
      }
    }
    float z = acc0 + acc1 + bf2f(gcur);
    z_lds[tid] = z;
    __syncthreads();
    if (tid < 128) {
      float zi = z_lds[tid], zj = z_lds[128 + tid];
      float zf = z_lds[256 + tid], zo = z_lds[384 + tid];
      float fg = 1.0f / (1.0f + expf(-(zf + 1.0f)));   // FORGET_BIAS = 1.0
      float ig = 1.0f / (1.0f + expf(-zi));
      float og = 1.0f / (1.0f + expf(-zo));
      float cn = c * fg + ig * tanhf(zj);
      c = cn;
      float hn = tanhf(cn) * og;
      h_lds[tid] = hn;
      hs[((size_t)t_act * 128 + b) * 128 + tid] = hn;
    }
    __syncthreads();
    gcur = gnxt;
    t_act = t_next;
  }
}

// ---------------- attention + FC + argmax, one WG per batch row -------------------------------
__global__ __launch_bounds__(256) void k_attn(const float* __restrict__ hs_fw,
                                              const float* __restrict__ hs_bw,
                                              const float* __restrict__ att_w,
                                              const float* __restrict__ fc_w,
                                              const float* __restrict__ fc_b,
                                              float* __restrict__ out) {
  __shared__ float part[2][512];
  __shared__ float sc[512];
  __shared__ float red[256];
  __shared__ float rpart[256];
  __shared__ float hstar[128];
  __shared__ float lg[NCLS];
  int tid = threadIdx.x;
  int b = blockIdx.x;
  int h = tid & 127, g = tid >> 7;
  int wave_half = (tid >> 6) & 1;
  float aw = att_w[h];
  // phase 1: scores[t] = sum_h tanh(fw+bw) * att_w
  for (int it = 0; it < 256; it += 4) {
    float v[4];
#pragma unroll
    for (int u = 0; u < 4; u++) {
      int t = (it + u) * 2 + g;
      size_t o = ((size_t)t * 128 + b) * 128 + h;
      v[u] = hs_fw[o] + hs_bw[o];
    }
#pragma unroll
    for (int u = 0; u < 4; u++) {
      int t = (it + u) * 2 + g;
      float s = tanhf(v[u]) * aw;
#pragma unroll
      for (int o2 = 32; o2 >= 1; o2 >>= 1) s += __shfl_xor(s, o2, 64);
      if ((tid & 63) == 0) part[wave_half][t] = s;
    }
  }
  __syncthreads();
  for (int t = tid; t < 512; t += 256) sc[t] = part[0][t] + part[1][t];
  __syncthreads();
  // softmax over 512 scores
  float lm = fmaxf(sc[tid], sc[tid + 256]);
  red[tid] = lm; __syncthreads();
  for (int s = 128; s >= 1; s >>= 1) {
    if (tid < s) red[tid] = fmaxf(red[tid], red[tid + s]);
    __syncthreads();
  }
  float mx = red[0];
  __syncthreads();
  float le = 0.f;
  for (int t = tid; t < 512; t += 256) { float e = expf(sc[t] - mx); sc[t] = e; le += e; }
  red[tid] = le; __syncthreads();
  for (int s = 128; s >= 1; s >>= 1) {
    if (tid < s) red[tid] += red[tid + s];
    __syncthreads();
  }
  float invS = 1.0f / red[0];
  __syncthreads();
  // phase 2: r[h] = (sum_t e[t]*(fw+bw)) * invS
  float racc = 0.f;
  for (int it = 0; it < 256; it += 4) {
    float v[4], a[4];
#pragma unroll
    for (int u = 0; u < 4; u++) {
      int t = (it + u) * 2 + g;
      size_t o = ((size_t)t * 128 + b) * 128 + h;
      v[u] = hs_fw[o] + hs_bw[o];
      a[u] = sc[t];
    }
#pragma unroll
    for (int u = 0; u < 4; u++) racc = fmaf(a[u], v[u], racc);
  }
  rpart[tid] = racc;
  __syncthreads();
  if (tid < 128) {
    float r = (rpart[tid] + rpart[128 + tid]) * invS;
    hstar[tid] = tanhf(r);
  }
  __syncthreads();
  if (tid < NCLS) {
    float acc = fc_b[tid];
#pragma unroll 4
    for (int hh = 0; hh < 128; hh++) acc = fmaf(hstar[hh], fc_w[hh * NCLS + tid], acc);
    out[b * NCLS + tid] = acc;
    lg[tid] = acc;
  }
  __syncthreads();
  if (tid == 0) {
    int best = 0; float bv = lg[0];
    for (int l2 = 1; l2 < NCLS; l2++)
      if (lg[l2] > bv) { bv = lg[l2]; best = l2; }
    out[2432 + b] = (float)best;   // predict_label_ids
    out[2561 + b] = (float)best;   // probabilities (argmax of softmax == argmax)
  }
}

// ---------------- l2 loss ---------------------------------------------------------------------
__global__ __launch_bounds__(256) void k_l2(const float* __restrict__ fc_w,
                                            const float* __restrict__ fc_b,
                                            float* __restrict__ out) {
  __shared__ float red[256];
  int tid = threadIdx.x;
  float a = 0.f;
  for (int i = tid; i < 128 * NCLS; i += 256) a += fc_w[i] * fc_w[i];
  if (tid < NCLS) a += fc_b[tid] * fc_b[tid];
  red[tid] = a; __syncthreads();
  for (int s = 128; s >= 1; s >>= 1) {
    if (tid < s) red[tid] += red[tid + s];
    __syncthreads();
  }
  if (tid == 0) out[2560] = 0.5f * red[0];
}

extern "C" void kernel_launch(void* const* d_in, const int* in_sizes, int n_in,
                              void* d_out, int out_size, void* d_ws, size_t ws_size,
                              hipStream_t stream) {
  const int* ids = (const int*)d_in[0];
  const float* table = (const float*)d_in[1];
  const float* fw_k = (const float*)d_in[2];
  const float* fw_b = (const float*)d_in[3];
  const float* bw_k = (const float*)d_in[4];
  const float* bw_b = (const float*)d_in[5];
  const float* att_w = (const float*)d_in[6];
  const float* fc_w = (const float*)d_in[7];
  const float* fc_b = (const float*)d_in[8];
  float* out = (float*)d_out;
  char* ws = (char*)d_ws;

  u16* xs = (u16*)(ws + 0);                    // 16,777,216 B
  u16* wx_t = (u16*)(ws + 16777216);           //    262,144 B
  float* wh_t = (float*)(ws + 17039360);       //    524,288 B
  float* bias_cat = (float*)(ws + 17563648);   //      4,096 B
  u16* gates = (u16*)(ws + 17567744);          // 134,217,728 B
  float* hs_fw = (float*)(ws + 151785472);     // 33,554,432 B
  float* hs_bw = (float*)(ws + 185339904);     // 33,554,432 B  (end 218,894,336)

  hipLaunchKernelGGL(k_embed, dim3(8192), dim3(256), 0, stream, ids, table, xs);
  hipLaunchKernelGGL(k_prep, dim3(1025), dim3(256), 0, stream, fw_k, bw_k, fw_b, bw_b,
                     wx_t, wh_t, bias_cat);
  hipLaunchKernelGGL(k_gemm, dim3(512, 8), dim3(256), 0, stream, xs, wx_t, bias_cat, gates);
  hipLaunchKernelGGL(k_lstm, dim3(256), dim3(512), 0, stream, wh_t, gates, hs_fw, hs_bw);
  hipLaunchKernelGGL(k_attn, dim3(128), dim3(256), 0, stream, hs_fw, hs_bw, att_w, fc_w, fc_b, out);
  hipLaunchKernelGGL(k_l2, dim3(1), dim3(256), 0, stream, fc_w, fc_b, out);
}

// Round 2
// 600.782 us; speedup vs baseline: 1.0892x; 1.0892x over previous
//
#include <hip/hip_runtime.h>

typedef unsigned short u16;
typedef unsigned int u32;
typedef short short8 __attribute__((ext_vector_type(8)));
typedef float f32x4 __attribute__((ext_vector_type(4)));

#define T_LEN 512
#define BATCH 128
#define DIM 128
#define HID 128
#define G4H 512
#define NCLS 19
#define GATES_HALF 33554432u  // 65536*512 elements per direction

static __device__ __forceinline__ u16 f2bf(float f) {
  u32 u = __float_as_uint(f);
  u32 r = (u + 0x7FFFu + ((u >> 16) & 1u)) >> 16;
  return (u16)r;
}
static __device__ __forceinline__ float bf2f(u16 h) {
  return __uint_as_float(((u32)h) << 16);
}

// ---------------- embedding gather + cast to bf16, layout xs[t*B+b][d] -------------
__global__ __launch_bounds__(256) void k_embed(const int* __restrict__ ids,
                                               const float* __restrict__ table,
                                               u16* __restrict__ xs) {
  int i = blockIdx.x * 256 + threadIdx.x;
  int e = i * 4;               // element index, total T*B*D = 8388608
  int m = e >> 7;              // row = t*B + b
  int col = e & 127;
  int t = m >> 7, b = m & 127;
  int id = ids[b * T_LEN + t];
  float4 v = *(const float4*)(table + (size_t)id * DIM + col);
  ushort4 o;
  o.x = f2bf(v.x); o.y = f2bf(v.y); o.z = f2bf(v.z); o.w = f2bf(v.w);
  *(ushort4*)(xs + (size_t)m * DIM + col) = o;
}

// ---------------- weight prep (gate-interleaved permutation p = u*4+q <-> j = q*128+u) --------
// wx_t row n = dir*512 + p holds original column j(p); bias_cat likewise; wh_t[dir][p][k].
// k_gemm then emits gates already permuted; k_lstm thread tid reads column tid (coalesced).
__global__ __launch_bounds__(256) void k_prep(const float* __restrict__ fw_k,
                                              const float* __restrict__ bw_k,
                                              const float* __restrict__ fw_b,
                                              const float* __restrict__ bw_b,
                                              u16* __restrict__ wx_t,
                                              float* __restrict__ wh_t,
                                              float* __restrict__ bias_cat) {
  int wg = blockIdx.x;
  int tid = threadIdx.x;
  if (wg < 512) {                 // wx_t[n][k] = K_dir[k][j(p)]
    int i = wg * 256 + tid;       // 0..131071
    int n = i >> 7, k = i & 127;
    int dir = n >> 9, p = n & 511;
    int u = p >> 2, q = p & 3;
    int j = q * 128 + u;
    const float* K = dir ? bw_k : fw_k;
    wx_t[i] = f2bf(K[k * G4H + j]);
  } else if (wg < 1024) {         // wh_t[dir][p][k] = K_dir[128+k][j(p)]
    int i = (wg - 512) * 256 + tid;
    int dir = i >> 16;
    int p = (i >> 7) & 511, k = i & 127;
    int u = p >> 2, q = p & 3;
    int j = q * 128 + u;
    const float* K = dir ? bw_k : fw_k;
    wh_t[i] = K[(128 + k) * G4H + j];
  } else {
    for (int uu = 0; uu < 4; uu++) {
      int n = uu * 256 + tid;
      int dir = n >> 9, p = n & 511;
      int u = p >> 2, q = p & 3;
      int j = q * 128 + u;
      bias_cat[n] = (dir ? bw_b : fw_b)[j];
    }
  }
}

// ---------------- input projection GEMM: [65536,128] @ [128,1024] bf16 MFMA -> bf16 gates ------
__global__ __launch_bounds__(256, 2) void k_gemm(const u16* __restrict__ xs,
                                                 const u16* __restrict__ wx_t,
                                                 const float* __restrict__ bias_cat,
                                                 u16* __restrict__ gates) {
  __shared__ u16 As[128 * 136];
  __shared__ u16 Bs[128 * 136];
  int tid = threadIdx.x;
  int m0 = blockIdx.x * 128;
  int n0 = blockIdx.y * 128;
  const u16* Asrc = xs + (size_t)m0 * 128;     // contiguous 32KB tile
  const u16* Bsrc = wx_t + (size_t)n0 * 128;   // contiguous 32KB tile (pre-transposed)
#pragma unroll
  for (int i = 0; i < 8; i++) {
    int c = i * 256 + tid;            // 0..2047 chunks of 16B
    int row = c >> 4, off = (c & 15) * 8;
    short8 va = *(const short8*)(Asrc + row * 128 + off);
    *(short8*)(As + row * 136 + off) = va;
    short8 vb = *(const short8*)(Bsrc + row * 128 + off);
    *(short8*)(Bs + row * 136 + off) = vb;
  }
  __syncthreads();
  int l = tid & 63, w = tid >> 6;
  int wm = w & 1, wn = w >> 1;
  int lr = l & 15, lk = (l >> 4) * 8;
  f32x4 acc[4][4];
#pragma unroll
  for (int a = 0; a < 4; a++)
#pragma unroll
    for (int b2 = 0; b2 < 4; b2++) acc[a][b2] = (f32x4){0.f, 0.f, 0.f, 0.f};
#pragma unroll
  for (int ks = 0; ks < 4; ks++) {
    int k = ks * 32 + lk;
    short8 af[4], bf[4];
#pragma unroll
    for (int fm = 0; fm < 4; fm++)
      af[fm] = *(const short8*)(As + (wm * 64 + fm * 16 + lr) * 136 + k);
#pragma unroll
    for (int fn = 0; fn < 4; fn++)
      bf[fn] = *(const short8*)(Bs + (wn * 64 + fn * 16 + lr) * 136 + k);
#pragma unroll
    for (int fm = 0; fm < 4; fm++)
#pragma unroll
      for (int fn = 0; fn < 4; fn++)
        acc[fm][fn] = __builtin_amdgcn_mfma_f32_16x16x32_bf16(af[fm], bf[fn], acc[fm][fn], 0, 0, 0);
  }
#pragma unroll
  for (int fm = 0; fm < 4; fm++) {
#pragma unroll
    for (int fn = 0; fn < 4; fn++) {
      int gcol = n0 + wn * 64 + fn * 16 + lr;
      int dir = gcol >> 9, j = gcol & 511;
      float bsv = bias_cat[gcol];
#pragma unroll
      for (int i2 = 0; i2 < 4; i2++) {
        int grow = m0 + wm * 64 + fm * 16 + (l >> 4) * 4 + i2;
        float v = acc[fm][fn][i2] + bsv;
        gates[(size_t)dir * GATES_HALF + (size_t)grow * 512 + j] = f2bf(v);
      }
    }
  }
}

// ---------------- persistent LSTM: 256 WGs (dir x batch), thread = gate q of unit u -----------
__global__ __launch_bounds__(512, 2) void k_lstm(const float* __restrict__ wh_t,
                                                 const u16* __restrict__ gates,
                                                 float* __restrict__ hs_fw,
                                                 float* __restrict__ hs_bw) {
  __shared__ float hbuf[2][128];
  int tid = threadIdx.x;
  int wg = blockIdx.x;
  int dir = wg >> 7;
  int b = wg & 127;
  int u = tid >> 2, q = tid & 3;          // gate q of hidden unit u (permuted layout)
  float* hs = dir ? hs_bw : hs_fw;
  const u16* g_base = gates + (size_t)dir * GATES_HALF;

  // recurrent weights for my (permuted) column, fp32 in VGPRs
  float wv[128];
  const float4* wsrc = (const float4*)(wh_t + ((size_t)(dir * 512 + tid)) * 128);
#pragma unroll
  for (int i = 0; i < 32; i++) {
    float4 v = wsrc[i];
    wv[4 * i + 0] = v.x; wv[4 * i + 1] = v.y;
    wv[4 * i + 2] = v.z; wv[4 * i + 3] = v.w;
  }
  // per-gate activation constants: val = postm * sigmoid(presc*z + badd) + postb
  // q=0 (i): sig(z); q=1 (cand): tanh(z)=2*sig(2z)-1; q=2 (f): sig(z+1); q=3 (o): sig(z)
  float presc = (q == 1) ? 2.0f : 1.0f;
  float badd  = (q == 2) ? 1.0f : 0.0f;
  float postm = (q == 1) ? 2.0f : 1.0f;
  float postb = (q == 1) ? -1.0f : 0.0f;
  int lane = tid & 63;
  int base = lane & ~3;

  if (tid < 128) hbuf[0][tid] = 0.0f;
  float c = 0.0f;
  __syncthreads();

  int t0 = dir ? (T_LEN - 1) : 0;
  int stp = dir ? -1 : 1;
  const u16* gp = g_base + ((size_t)(t0 * 128 + b)) * 512 + tid;
  long gd = (long)stp * 65536;            // elements per time step
  float* hw = hs + ((size_t)(t0 * 128 + b)) * 128 + u;
  long hd = (long)stp * 16384;

  u16 gc = gp[0];                         // gate for step 0
  u16 gn = *(gp + gd);                    // gate for step 1
  const u16* gp2 = gp + 2 * gd;           // prefetch pointer (depth 2)

  for (int t = 0; t < T_LEN; t++) {
    u16 gf = 0;
    if (t < T_LEN - 2) gf = *gp2;         // prefetch step t+2 (stays in flight across barrier)
    gp2 += gd;

    const float4* h4 = (const float4*)hbuf[t & 1];
    float a0 = 0.f, a1 = 0.f, a2 = 0.f, a3 = 0.f;
    float a4 = 0.f, a5 = 0.f, a6 = 0.f, a7 = 0.f;
#pragma unroll
    for (int i = 0; i < 16; i++) {
      float4 x = h4[2 * i];
      float4 y = h4[2 * i + 1];
      a0 = fmaf(wv[8 * i + 0], x.x, a0);
      a1 = fmaf(wv[8 * i + 1], x.y, a1);
      a2 = fmaf(wv[8 * i + 2], x.z, a2);
      a3 = fmaf(wv[8 * i + 3], x.w, a3);
      a4 = fmaf(wv[8 * i + 4], y.x, a4);
      a5 = fmaf(wv[8 * i + 5], y.y, a5);
      a6 = fmaf(wv[8 * i + 6], y.z, a6);
      a7 = fmaf(wv[8 * i + 7], y.w, a7);
    }
    float z = ((a0 + a1) + (a2 + a3)) + ((a4 + a5) + (a6 + a7)) + bf2f(gc);
    // own-gate activation only (1 exp + 1 rcp per lane)
    float xx = fmaf(presc, z, badd);
    float s = 1.0f / (1.0f + __expf(-xx));
    float val = fmaf(postm, s, postb);
    // in-wave exchange: lanes base..base+3 hold i, cand, f, o of unit u
    float ig = __shfl(val, base + 0, 64);
    float tj = __shfl(val, base + 1, 64);
    float fg = __shfl(val, base + 2, 64);
    float og = __shfl(val, base + 3, 64);
    c = fmaf(c, fg, ig * tj);             // each of the 4 lanes keeps identical c
    float e2 = __expf(2.0f * c);
    float hn = (1.0f - 2.0f / (e2 + 1.0f)) * og;   // tanh(c)*og
    if (q == 0) {
      hbuf[(t + 1) & 1][u] = hn;
      *hw = hn;
    }
    hw += hd;
    // single barrier per step: drain LDS only — gate prefetch (vmcnt) stays in flight
    asm volatile("s_waitcnt lgkmcnt(0)" ::: "memory");
    __builtin_amdgcn_s_barrier();
    asm volatile("" ::: "memory");
    gc = gn; gn = gf;
  }
}

// ---------------- attention + FC + argmax, one WG per batch row -------------------------------
__global__ __launch_bounds__(256) void k_attn(const float* __restrict__ hs_fw,
                                              const float* __restrict__ hs_bw,
                                              const float* __restrict__ att_w,
                                              const float* __restrict__ fc_w,
                                              const float* __restrict__ fc_b,
                                              float* __restrict__ out) {
  __shared__ float part[2][512];
  __shared__ float sc[512];
  __shared__ float red[256];
  __shared__ float rpart[256];
  __shared__ float hstar[128];
  __shared__ float lg[NCLS];
  int tid = threadIdx.x;
  int b = blockIdx.x;
  int h = tid & 127, g = tid >> 7;
  int wave_half = (tid >> 6) & 1;
  float aw = att_w[h];
  // phase 1: scores[t] = sum_h tanh(fw+bw) * att_w
  for (int it = 0; it < 256; it += 4) {
    float v[4];
#pragma unroll
    for (int u = 0; u < 4; u++) {
      int t = (it + u) * 2 + g;
      size_t o = ((size_t)t * 128 + b) * 128 + h;
      v[u] = hs_fw[o] + hs_bw[o];
    }
#pragma unroll
    for (int u = 0; u < 4; u++) {
      int t = (it + u) * 2 + g;
      float s = tanhf(v[u]) * aw;
#pragma unroll
      for (int o2 = 32; o2 >= 1; o2 >>= 1) s += __shfl_xor(s, o2, 64);
      if ((tid & 63) == 0) part[wave_half][t] = s;
    }
  }
  __syncthreads();
  for (int t = tid; t < 512; t += 256) sc[t] = part[0][t] + part[1][t];
  __syncthreads();
  // softmax over 512 scores
  float lm = fmaxf(sc[tid], sc[tid + 256]);
  red[tid] = lm; __syncthreads();
  for (int s = 128; s >= 1; s >>= 1) {
    if (tid < s) red[tid] = fmaxf(red[tid], red[tid + s]);
    __syncthreads();
  }
  float mx = red[0];
  __syncthreads();
  float le = 0.f;
  for (int t = tid; t < 512; t += 256) { float e = expf(sc[t] - mx); sc[t] = e; le += e; }
  red[tid] = le; __syncthreads();
  for (int s = 128; s >= 1; s >>= 1) {
    if (tid < s) red[tid] += red[tid + s];
    __syncthreads();
  }
  float invS = 1.0f / red[0];
  __syncthreads();
  // phase 2: r[h] = (sum_t e[t]*(fw+bw)) * invS
  float racc = 0.f;
  for (int it = 0; it < 256; it += 4) {
    float v[4], a[4];
#pragma unroll
    for (int u = 0; u < 4; u++) {
      int t = (it + u) * 2 + g;
      size_t o = ((size_t)t * 128 + b) * 128 + h;
      v[u] = hs_fw[o] + hs_bw[o];
      a[u] = sc[t];
    }
#pragma unroll
    for (int u = 0; u < 4; u++) racc = fmaf(a[u], v[u], racc);
  }
  rpart[tid] = racc;
  __syncthreads();
  if (tid < 128) {
    float r = (rpart[tid] + rpart[128 + tid]) * invS;
    hstar[tid] = tanhf(r);
  }
  __syncthreads();
  if (tid < NCLS) {
    float acc = fc_b[tid];
#pragma unroll 4
    for (int hh = 0; hh < 128; hh++) acc = fmaf(hstar[hh], fc_w[hh * NCLS + tid], acc);
    out[b * NCLS + tid] = acc;
    lg[tid] = acc;
  }
  __syncthreads();
  if (tid == 0) {
    int best = 0; float bv = lg[0];
    for (int l2 = 1; l2 < NCLS; l2++)
      if (lg[l2] > bv) { bv = lg[l2]; best = l2; }
    out[2432 + b] = (float)best;   // predict_label_ids
    out[2561 + b] = (float)best;   // probabilities (argmax of softmax == argmax)
  }
}

// ---------------- l2 loss ---------------------------------------------------------------------
__global__ __launch_bounds__(256) void k_l2(const float* __restrict__ fc_w,
                                            const float* __restrict__ fc_b,
                                            float* __restrict__ out) {
  __shared__ float red[256];
  int tid = threadIdx.x;
  float a = 0.f;
  for (int i = tid; i < 128 * NCLS; i += 256) a += fc_w[i] * fc_w[i];
  if (tid < NCLS) a += fc_b[tid] * fc_b[tid];
  red[tid] = a; __syncthreads();
  for (int s = 128; s >= 1; s >>= 1) {
    if (tid < s) red[tid] += red[tid + s];
    __syncthreads();
  }
  if (tid == 0) out[2560] = 0.5f * red[0];
}

extern "C" void kernel_launch(void* const* d_in, const int* in_sizes, int n_in,
                              void* d_out, int out_size, void* d_ws, size_t ws_size,
                              hipStream_t stream) {
  const int* ids = (const int*)d_in[0];
  const float* table = (const float*)d_in[1];
  const float* fw_k = (const float*)d_in[2];
  const float* fw_b = (const float*)d_in[3];
  const float* bw_k = (const float*)d_in[4];
  const float* bw_b = (const float*)d_in[5];
  const float* att_w = (const float*)d_in[6];
  const float* fc_w = (const float*)d_in[7];
  const float* fc_b = (const float*)d_in[8];
  float* out = (float*)d_out;
  char* ws = (char*)d_ws;

  u16* xs = (u16*)(ws + 0);                    // 16,777,216 B
  u16* wx_t = (u16*)(ws + 16777216);           //    262,144 B
  float* wh_t = (float*)(ws + 17039360);       //    524,288 B
  float* bias_cat = (float*)(ws + 17563648);   //      4,096 B
  u16* gates = (u16*)(ws + 17567744);          // 134,217,728 B
  float* hs_fw = (float*)(ws + 151785472);     // 33,554,432 B
  float* hs_bw = (float*)(ws + 185339904);     // 33,554,432 B  (end 218,894,336)

  hipLaunchKernelGGL(k_embed, dim3(8192), dim3(256), 0, stream, ids, table, xs);
  hipLaunchKernelGGL(k_prep, dim3(1025), dim3(256), 0, stream, fw_k, bw_k, fw_b, bw_b,
                     wx_t, wh_t, bias_cat);
  hipLaunchKernelGGL(k_gemm, dim3(512, 8), dim3(256), 0, stream, xs, wx_t, bias_cat, gates);
  hipLaunchKernelGGL(k_lstm, dim3(256), dim3(512), 0, stream, wh_t, gates, hs_fw, hs_bw);
  hipLaunchKernelGGL(k_attn, dim3(128), dim3(256), 0, stream, hs_fw, hs_bw, att_w, fc_w, fc_b, out);
  hipLaunchKernelGGL(k_l2, dim3(1), dim3(256), 0, stream, fc_w, fc_b, out);
}